// Round 3
// baseline (592.067 us; speedup 1.0000x reference)
//
#include <hip/hip_runtime.h>

#define GP 256          // virtual partition grid (fixed, independent of real grid)
#define MAXNB 4096      // max coarse buckets (n <= 512k)
#define BCAP 2688       // LDS edge buffer for single-pass bucket CSR

using bf16x8 = __attribute__((ext_vector_type(8))) short;
using f32x4 = __attribute__((ext_vector_type(4))) float;

// bf16 helpers (self-contained, RNE)
static __device__ __forceinline__ unsigned short f2bf(float f) {
  unsigned u = __float_as_uint(f);
  unsigned r = (u + 0x7fff + ((u >> 16) & 1)) >> 16;
  return (unsigned short)r;
}
static __device__ __forceinline__ float bflo(unsigned w) {
  return __uint_as_float(w << 16);
}
static __device__ __forceinline__ float bfhi(unsigned w) {
  return __uint_as_float(w & 0xffff0000u);
}
static __device__ __forceinline__ unsigned pk2(float a, float b) {
  return (unsigned)f2bf(a) | ((unsigned)f2bf(b) << 16);
}

// Software grid barrier: monotonic counter, device-scope atomics, agent fences.
// Safe because grid is sized to guaranteed co-residency (occupancy query).
static __device__ __forceinline__ void gridbar(int* cnt, int target) {
  __syncthreads();
  if (threadIdx.x == 0) {
    __threadfence();  // release: drain + write-back so other XCDs see our stores
    __hip_atomic_fetch_add(cnt, 1, __ATOMIC_RELAXED, __HIP_MEMORY_SCOPE_AGENT);
    while (__hip_atomic_load(cnt, __ATOMIC_RELAXED, __HIP_MEMORY_SCOPE_AGENT) <
           target)
      __builtin_amdgcn_s_sleep(2);
    __threadfence();  // acquire: invalidate so we see other XCDs' stores
  }
  __syncthreads();
}

// ======================= the megakernel =======================
// Phases (6 grid barriers):
// P0 hist (+guard-row zero) | P1 chunk scan | P3 partition (+local bsum scan)
// P4 bucket CSR (+dinv)     | P5 gemm1      | P6 agg1+relu+b1+gemm2 fused
// P7 agg2 (+b2, f32 out)
// __launch_bounds__(256, 2): min 2 waves/EU -> VGPR cap 256. Round-2 lesson:
// without this the allocator picked 56 VGPRs and spilled the gather
// accumulators to scratch (WRITE_SIZE 100MB vs 37MB real, VALUBusy 4%).

__global__ void __launch_bounds__(256, 2) k_mega(
    const float* __restrict__ x, const int* __restrict__ src,
    const int* __restrict__ dst, const float* __restrict__ W1,
    const float* __restrict__ b1, const float* __restrict__ W2,
    const float* __restrict__ b2, int* __restrict__ C, int* __restrict__ Cs,
    int* __restrict__ bsum, int* __restrict__ bpack, int* __restrict__ rp,
    int* __restrict__ csr_src, float* __restrict__ dinv,
    unsigned short* __restrict__ h1b, unsigned short* __restrict__ h2b,
    float* __restrict__ out, int* __restrict__ barcnt, int n, int e, int NB, int m,
    int NC, int chunk) {
  __shared__ __align__(16) char lds_raw[32 * 1024];
  const int t = threadIdx.x;
  const int blk = blockIdx.x;
  const int G = gridDim.x;
  int bphase = 0;

  // ---------------- P0: guard-row zero + coarse histogram ----------------
  if (blk == 0) {
    unsigned* h1u = (unsigned*)h1b;
    unsigned* h2u = (unsigned*)h2b;
    if (t < 32) h1u[(size_t)n * 32 + t] = 0u;
    else if (t < 48) h2u[(size_t)n * 16 + (t - 32)] = 0u;
  }
  {
    int* h = (int*)lds_raw;
    for (int pb = blk; pb < GP; pb += G) {
      __syncthreads();
      for (int i = t; i < NB; i += 256) h[i] = 0;
      __syncthreads();
      int beg = pb * chunk;
      int stop = min(e, beg + chunk);
      for (int j = beg + t; j < stop; j += 256) atomicAdd(&h[dst[j] >> 7], 1);
      __syncthreads();
      for (int i = t; i < NB; i += 256) C[i * GP + pb] = h[i];
    }
  }
  gridbar(barcnt, ++bphase * G);

  // ---------------- P1: per-chunk scan of C -> Cs, chunk sums -> bsum ----
  {
    int* s = (int*)lds_raw;
    for (int c = blk; c < NC; c += G) {
      __syncthreads();
      int base = c * 1024 + t * 4;
      int v[4];
      int sum = 0;
#pragma unroll
      for (int k = 0; k < 4; ++k) {
        int i = base + k;
        v[k] = (i < m) ? C[i] : 0;
        sum += v[k];
      }
      s[t] = sum;
      __syncthreads();
      int mine = sum;
      for (int off = 1; off < 256; off <<= 1) {
        int y = (t >= off) ? s[t - off] : 0;
        __syncthreads();
        s[t] += y;
        __syncthreads();
      }
      int run = s[t] - mine;
      if (t == 255) bsum[c] = s[255];
#pragma unroll
      for (int k = 0; k < 4; ++k) {
        int i = base + k;
        if (i <= m) Cs[i] = run;
        run += v[k];
      }
    }
  }
  gridbar(barcnt, ++bphase * G);

  // ---------------- local bsum scan (every block, kept in LDS) -----------
  // sb[0..NC) = exclusive prefix of bsum. Persists through P3 and P4.
  int* sb = (int*)lds_raw;          // 1024 ints
  {
    int* ss = sb + 1024;            // 256 ints
    int v4[4];
    int b4 = t * 4;
    int sum = 0;
#pragma unroll
    for (int k = 0; k < 4; ++k) {
      int i = b4 + k;
      v4[k] = (i < NC) ? bsum[i] : 0;
      sum += v4[k];
    }
    ss[t] = sum;
    __syncthreads();
    int mine = sum;
    for (int off = 1; off < 256; off <<= 1) {
      int y = (t >= off) ? ss[t - off] : 0;
      __syncthreads();
      ss[t] += y;
      __syncthreads();
    }
    int run = ss[t] - mine;
#pragma unroll
    for (int k = 0; k < 4; ++k) {
      int i = b4 + k;
      if (i < NC) sb[i] = run;
      run += v4[k];
    }
    __syncthreads();
  }

  // ---------------- P3: partition edges into bucket-major bpack ----------
  {
    int* cur = (int*)lds_raw + 1280;  // MAXNB ints @ byte 5120
    for (int pb = blk; pb < GP; pb += G) {
      __syncthreads();
      for (int i = t; i < NB; i += 256) {
        int f = i * GP + pb;
        cur[i] = Cs[f] + sb[f >> 10];
      }
      __syncthreads();
      int beg = pb * chunk;
      int stop = min(e, beg + chunk);
      for (int j = beg + t; j < stop; j += 256) {
        int d = dst[j];
        int b = d >> 7;
        int pos = atomicAdd(&cur[b], 1);
        bpack[pos] = (src[j] << 7) | (d & 127);
      }
    }
  }
  gridbar(barcnt, ++bphase * G);

  // ---------------- P4: per-bucket CSR build + dinv ----------------------
  {
    int* cl = (int*)lds_raw + 1280;   // 128 ints @ 5120
    int* cur = cl + 128;              // 128 ints @ 5632
    int* buf = cur + 128;             // BCAP ints @ 6144
    if (blk == 0 && t == 0) rp[n] = e;
    for (int b = blk; b < NB; b += G) {
      __syncthreads();
      int fb = b * GP;
      int base = Cs[fb] + sb[fb >> 10];
      int end2 = (b == NB - 1) ? e : (Cs[fb + GP] + sb[(fb + GP) >> 10]);
      int cnt = end2 - base;
      if (t < 128) cl[t] = 0;
      __syncthreads();
      if (cnt <= BCAP) {
        for (int j = base + t; j < end2; j += 256) {
          int p = bpack[j];
          buf[j - base] = p;
          atomicAdd(&cl[p & 127], 1);
        }
      } else {
        for (int j = base + t; j < end2; j += 256) atomicAdd(&cl[bpack[j] & 127], 1);
      }
      __syncthreads();
      int own = (t < 128) ? cl[t] : 0;
      for (int off = 1; off < 128; off <<= 1) {
        int y = (t >= off && t < 128) ? cl[t - off] : 0;
        __syncthreads();
        if (t < 128) cl[t] += y;
        __syncthreads();
      }
      if (t < 128) {
        int excl = cl[t] - own;
        int v = (b << 7) + t;
        if (v < n) {
          rp[v] = base + excl;
          dinv[v] = rsqrtf((float)own + 1.0f);
        }
        cur[t] = base + excl;
      }
      __syncthreads();
      if (cnt <= BCAP) {
        for (int j = t; j < cnt; j += 256) {
          int p = buf[j];
          int pos = atomicAdd(&cur[p & 127], 1);
          csr_src[pos] = p >> 7;
        }
      } else {
        for (int j = base + t; j < end2; j += 256) {
          int p = bpack[j];
          int pos = atomicAdd(&cur[p & 127], 1);
          csr_src[pos] = p >> 7;
        }
      }
    }
  }
  gridbar(barcnt, ++bphase * G);

  // ---------------- P5: gemm1  h1b[n][64] = dinv[r]*(x @ W1^T) -----------
  {
    uint4* sXb = (uint4*)lds_raw;             // 1024 uint4 = 16KB
    uint4* sWb = sXb + 1024;                  // 1024 uint4 = 16KB
    unsigned short* sOut = (unsigned short*)lds_raw;  // aliases sXb (8KB)
    const float4* x4 = (const float4*)x;
    const float4* W14 = (const float4*)W1;
    // stage W1 once (persists across tiles)
#pragma unroll
    for (int p = 0; p < 4; ++p) {
      int q = t + 256 * p;
      int c = q >> 4, s2 = q & 15;
      float4 v0 = W14[c * 32 + s2 * 2];
      float4 v1 = W14[c * 32 + s2 * 2 + 1];
      uint4 pk;
      pk.x = pk2(v0.x, v0.y);
      pk.y = pk2(v0.z, v0.w);
      pk.z = pk2(v1.x, v1.y);
      pk.w = pk2(v1.z, v1.w);
      sWb[c * 16 + (s2 ^ (c & 15))] = pk;
    }
    for (int tile = blk; tile * 64 < n; tile += G) {
      int rbase = tile * 64;
      __syncthreads();  // protect sXb writes vs prev iter's sOut reads (alias)
#pragma unroll
      for (int p = 0; p < 4; ++p) {
        int q = t + 256 * p;
        int r = q >> 4, s2 = q & 15;
        int gr = rbase + r;
        float4 v0 = make_float4(0.f, 0.f, 0.f, 0.f), v1 = v0;
        if (gr < n) {
          v0 = x4[(size_t)gr * 32 + s2 * 2];
          v1 = x4[(size_t)gr * 32 + s2 * 2 + 1];
        }
        uint4 pk;
        pk.x = pk2(v0.x, v0.y);
        pk.y = pk2(v0.z, v0.w);
        pk.z = pk2(v1.x, v1.y);
        pk.w = pk2(v1.z, v1.w);
        sXb[r * 16 + (s2 ^ (r & 15))] = pk;
      }
      __syncthreads();
      int lane = t & 63;
      int w = t >> 6;
      int l16 = lane & 15, quad = lane >> 4;
      int arow = w * 16 + l16;
      f32x4 acc0 = {0.f, 0.f, 0.f, 0.f};
      f32x4 acc1 = {0.f, 0.f, 0.f, 0.f};
      f32x4 acc2 = {0.f, 0.f, 0.f, 0.f};
      f32x4 acc3 = {0.f, 0.f, 0.f, 0.f};
#pragma unroll
      for (int kc = 0; kc < 4; ++kc) {
        int slot = kc * 4 + quad;
        uint4 ua = sXb[arow * 16 + (slot ^ (arow & 15))];
        bf16x8 a = *(bf16x8*)&ua;
        uint4 ub0 = sWb[(0 + l16) * 16 + (slot ^ l16)];
        uint4 ub1 = sWb[(16 + l16) * 16 + (slot ^ l16)];
        uint4 ub2 = sWb[(32 + l16) * 16 + (slot ^ l16)];
        uint4 ub3 = sWb[(48 + l16) * 16 + (slot ^ l16)];
        acc0 = __builtin_amdgcn_mfma_f32_16x16x32_bf16(a, *(bf16x8*)&ub0, acc0, 0, 0, 0);
        acc1 = __builtin_amdgcn_mfma_f32_16x16x32_bf16(a, *(bf16x8*)&ub1, acc1, 0, 0, 0);
        acc2 = __builtin_amdgcn_mfma_f32_16x16x32_bf16(a, *(bf16x8*)&ub2, acc2, 0, 0, 0);
        acc3 = __builtin_amdgcn_mfma_f32_16x16x32_bf16(a, *(bf16x8*)&ub3, acc3, 0, 0, 0);
      }
      float dvr[4];
#pragma unroll
      for (int r = 0; r < 4; ++r) {
        int grow = rbase + w * 16 + quad * 4 + r;
        dvr[r] = (grow < n) ? dinv[grow] : 0.f;
      }
      __syncthreads();  // all sXb reads done before sOut overwrites the alias
#pragma unroll
      for (int r = 0; r < 4; ++r) {
        int rl = w * 16 + quad * 4 + r;
        sOut[rl * 64 + 0 + l16] = f2bf(acc0[r] * dvr[r]);
        sOut[rl * 64 + 16 + l16] = f2bf(acc1[r] * dvr[r]);
        sOut[rl * 64 + 32 + l16] = f2bf(acc2[r] * dvr[r]);
        sOut[rl * 64 + 48 + l16] = f2bf(acc3[r] * dvr[r]);
      }
      __syncthreads();
#pragma unroll
      for (int p = 0; p < 2; ++p) {
        int q = t + 256 * p;
        int r = q >> 3, s2 = q & 7;
        int gr = rbase + r;
        if (gr < n)
          *(uint4*)&h1b[(size_t)gr * 64 + s2 * 8] = *(uint4*)&sOut[r * 64 + s2 * 8];
      }
    }
  }
  gridbar(barcnt, ++bphase * G);

  // ------- P6: fused agg1 (gather h1b) + relu(+b1) + gemm2 -> h2b --------
  {
    uint4* sXb2 = (uint4*)lds_raw;        // 512 uint4 = 8KB (64 rows x 64 bf16)
    uint4* sWb2 = sXb2 + 512;             // 256 uint4 = 4KB
    unsigned short* sOut2 = (unsigned short*)(sWb2 + 256);  // 4KB
    const uint2* h1q = (const uint2*)h1b;
    const float4* W24 = (const float4*)W2;
    const float4* b14 = (const float4*)b1;
    // stage W2 once
    {
      int c = t >> 3, s2 = t & 7;
      float4 v0 = W24[c * 16 + s2 * 2];
      float4 v1 = W24[c * 16 + s2 * 2 + 1];
      uint4 pk;
      pk.x = pk2(v0.x, v0.y);
      pk.y = pk2(v0.z, v0.w);
      pk.z = pk2(v1.x, v1.y);
      pk.w = pk2(v1.z, v1.w);
      sWb2[c * 8 + (s2 ^ (c & 7))] = pk;
    }
    int f4 = t & 15;
    int rloc = t >> 4;
    for (int tile = blk; tile * 64 < n; tile += G) {
      int rbase = tile * 64;
      __syncthreads();  // protect sXb2 writes vs prev iter MFMA reads / W2 staging
#pragma unroll
      for (int sub = 0; sub < 4; ++sub) {
        int r = sub * 16 + rloc;
        int v = rbase + r;
        float r0 = 0.f, r1 = 0.f, r2 = 0.f, r3 = 0.f;
        if (v < n) {
          int beg = rp[v], end = rp[v + 1];
          uint2 w0 = h1q[(size_t)v * 16 + f4];  // self (pre-scaled by dinv[v])
          float acc[4][4];
#pragma unroll
          for (int k = 0; k < 4; ++k)
#pragma unroll
            for (int c = 0; c < 4; ++c) acc[k][c] = 0.f;
          acc[0][0] = bflo(w0.x);
          acc[0][1] = bfhi(w0.x);
          acc[0][2] = bflo(w0.y);
          acc[0][3] = bfhi(w0.y);
          for (int j = beg; j < end; j += 4) {
            int s[4];
#pragma unroll
            for (int k = 0; k < 4; ++k) s[k] = csr_src[j + k];
#pragma unroll
            for (int k = 1; k < 4; ++k) s[k] = (j + k < end) ? s[k] : n;
            uint2 g[4];
#pragma unroll
            for (int k = 0; k < 4; ++k) g[k] = h1q[(size_t)s[k] * 16 + f4];
#pragma unroll
            for (int k = 0; k < 4; ++k) {
              acc[k][0] += bflo(g[k].x);
              acc[k][1] += bfhi(g[k].x);
              acc[k][2] += bflo(g[k].y);
              acc[k][3] += bfhi(g[k].y);
            }
          }
          float s0 = (acc[0][0] + acc[1][0]) + (acc[2][0] + acc[3][0]);
          float s1 = (acc[0][1] + acc[1][1]) + (acc[2][1] + acc[3][1]);
          float s2 = (acc[0][2] + acc[1][2]) + (acc[2][2] + acc[3][2]);
          float s3 = (acc[0][3] + acc[1][3]) + (acc[2][3] + acc[3][3]);
          float dv = dinv[v];
          float4 bb = b14[f4];
          r0 = fmaxf(fmaf(dv, s0, bb.x), 0.f);
          r1 = fmaxf(fmaf(dv, s1, bb.y), 0.f);
          r2 = fmaxf(fmaf(dv, s2, bb.z), 0.f);
          r3 = fmaxf(fmaf(dv, s3, bb.w), 0.f);
        }
        unsigned u0 = pk2(r0, r1), u1 = pk2(r2, r3);
        unsigned* xb = (unsigned*)sXb2;
        int slot = (f4 >> 1) ^ (r & 7);
        xb[(r * 8 + slot) * 4 + (f4 & 1) * 2 + 0] = u0;
        xb[(r * 8 + slot) * 4 + (f4 & 1) * 2 + 1] = u1;
      }
      __syncthreads();
      int lane = t & 63;
      int w = t >> 6;
      int l16 = lane & 15, quad = lane >> 4;
      int arow = w * 16 + l16;
      f32x4 acc0 = {0.f, 0.f, 0.f, 0.f};
      f32x4 acc1 = {0.f, 0.f, 0.f, 0.f};
#pragma unroll
      for (int kc = 0; kc < 2; ++kc) {
        int slot = kc * 4 + quad;
        uint4 ua = sXb2[arow * 8 + (slot ^ (arow & 7))];
        bf16x8 a = *(bf16x8*)&ua;
        uint4 ub0 = sWb2[l16 * 8 + (slot ^ (l16 & 7))];
        uint4 ub1 = sWb2[(16 + l16) * 8 + (slot ^ (l16 & 7))];
        acc0 = __builtin_amdgcn_mfma_f32_16x16x32_bf16(a, *(bf16x8*)&ub0, acc0, 0, 0, 0);
        acc1 = __builtin_amdgcn_mfma_f32_16x16x32_bf16(a, *(bf16x8*)&ub1, acc1, 0, 0, 0);
      }
      float dvr[4];
#pragma unroll
      for (int r = 0; r < 4; ++r) {
        int grow = rbase + w * 16 + quad * 4 + r;
        dvr[r] = (grow < n) ? dinv[grow] : 0.f;
      }
#pragma unroll
      for (int r = 0; r < 4; ++r) {
        int rl = w * 16 + quad * 4 + r;
        sOut2[rl * 32 + l16] = f2bf(acc0[r] * dvr[r]);
        sOut2[rl * 32 + 16 + l16] = f2bf(acc1[r] * dvr[r]);
      }
      __syncthreads();
      {
        int r = t >> 2, s2 = t & 3;
        int gr = rbase + r;
        if (gr < n)
          *(uint4*)&h2b[(size_t)gr * 32 + s2 * 8] = *(uint4*)&sOut2[r * 32 + s2 * 8];
      }
    }
  }
  gridbar(barcnt, ++bphase * G);

  // ---------------- P7: agg2 (gather h2b) + b2 -> f32 out ----------------
  {
    const uint2* h2q = (const uint2*)h2b;
    int total = n * 8;
    for (int g8 = blk * 256 + t; g8 < total; g8 += G * 256) {
      int v = g8 >> 3, f4 = g8 & 7;
      int beg = rp[v], end = rp[v + 1];
      uint2 w0 = h2q[(size_t)v * 8 + f4];  // self
      float acc[4][4];
#pragma unroll
      for (int k = 0; k < 4; ++k)
#pragma unroll
        for (int c = 0; c < 4; ++c) acc[k][c] = 0.f;
      acc[0][0] = bflo(w0.x);
      acc[0][1] = bfhi(w0.x);
      acc[0][2] = bflo(w0.y);
      acc[0][3] = bfhi(w0.y);
      for (int j = beg; j < end; j += 4) {
        int s[4];
#pragma unroll
        for (int k = 0; k < 4; ++k) s[k] = csr_src[j + k];
#pragma unroll
        for (int k = 1; k < 4; ++k) s[k] = (j + k < end) ? s[k] : n;
        uint2 g[4];
#pragma unroll
        for (int k = 0; k < 4; ++k) g[k] = h2q[(size_t)s[k] * 8 + f4];
#pragma unroll
        for (int k = 0; k < 4; ++k) {
          acc[k][0] += bflo(g[k].x);
          acc[k][1] += bfhi(g[k].x);
          acc[k][2] += bflo(g[k].y);
          acc[k][3] += bfhi(g[k].y);
        }
      }
      float s0 = (acc[0][0] + acc[1][0]) + (acc[2][0] + acc[3][0]);
      float s1 = (acc[0][1] + acc[1][1]) + (acc[2][1] + acc[3][1]);
      float s2 = (acc[0][2] + acc[1][2]) + (acc[2][2] + acc[3][2]);
      float s3 = (acc[0][3] + acc[1][3]) + (acc[2][3] + acc[3][3]);
      float dv = dinv[v];
      float4 bv = ((const float4*)b2)[f4];
      float4 o;
      o.x = fmaf(dv, s0, bv.x);
      o.y = fmaf(dv, s1, bv.y);
      o.z = fmaf(dv, s2, bv.z);
      o.w = fmaf(dv, s3, bv.w);
      ((float4*)out)[(size_t)v * 8 + f4] = o;
    }
  }
}

// ======================= launcher =======================

extern "C" void kernel_launch(void* const* d_in, const int* in_sizes, int n_in,
                              void* d_out, int out_size, void* d_ws, size_t ws_size,
                              hipStream_t stream) {
  const float* x = (const float*)d_in[0];
  const int* ei = (const int*)d_in[1];
  const float* W1 = (const float*)d_in[2];
  const float* b1 = (const float*)d_in[3];
  const float* W2 = (const float*)d_in[4];
  const float* b2 = (const float*)d_in[5];
  float* out = (float*)d_out;

  const int n = in_sizes[0] / 128;  // 100000
  const int e = in_sizes[1] / 2;    // 1600000
  const int* src = ei;
  const int* dst = ei + e;

  const int NB = (n + 127) >> 7;          // coarse buckets (782)
  const int m = NB * GP;                  // count-matrix size
  const int chunk = (e + GP - 1) / GP;    // edges per virtual partition block
  const int NC = (m + 1 + 1023) / 1024;   // scan chunks (196)

  char* base = (char*)d_ws;
  size_t off = 0;
  auto alloc = [&](size_t bytes) {
    char* p = base + off;
    off = (off + bytes + 255) & ~(size_t)255;
    return p;
  };
  int* C = (int*)alloc((size_t)m * 4);
  int* Cs = (int*)alloc((size_t)(m + 1) * 4);
  int* bsum = (int*)alloc(1024 * 4);
  int* bpack = (int*)alloc((size_t)e * 4);
  int* rp = (int*)alloc((size_t)(n + 1) * 4);
  int* csr_src = (int*)alloc((size_t)(e + 8) * 4);  // +8 pad for unrolled reads
  float* dinv = (float*)alloc((size_t)n * 4);
  unsigned short* h1b = (unsigned short*)alloc((size_t)(n + 1) * 64 * 2);  // bf16
  unsigned short* h2b = (unsigned short*)alloc((size_t)(n + 1) * 32 * 2);  // bf16
  int* barcnt = (int*)alloc(256);

  // One-time grid sizing: guaranteed-co-resident persistent grid.
  static int s_grid = 0;
  if (s_grid == 0) {
    int bpc = 0;
    hipError_t err = hipOccupancyMaxActiveBlocksPerMultiprocessor(&bpc, k_mega, 256, 0);
    int cu = 256;
    hipDeviceProp_t prop;
    if (hipGetDeviceProperties(&prop, 0) == hipSuccess &&
        prop.multiProcessorCount > 0)
      cu = prop.multiProcessorCount;
    if (err != hipSuccess || bpc < 1) bpc = 1;
    long long g = (long long)bpc * cu;
    if (g > 1024) g = 1024;
    if (g < 1) g = 1;
    s_grid = (int)g;
  }

  hipMemsetAsync(barcnt, 0, 256, stream);
  k_mega<<<s_grid, 256, 0, stream>>>(x, src, dst, W1, b1, W2, b2, C, Cs, bsum, bpack,
                                     rp, csr_src, dinv, h1b, h2b, out, barcnt, n, e,
                                     NB, m, NC, chunk);
}

// Round 4
// 205.178 us; speedup vs baseline: 2.8856x; 2.8856x over previous
//
#include <hip/hip_runtime.h>

#define THREADS 256
#define G1 256          // partition blocks
#define MAXNB 4096      // max coarse buckets (n <= 512k)
#define BCAP 2688       // LDS edge buffer for single-pass bucket CSR

using bf16x8 = __attribute__((ext_vector_type(8))) short;
using f32x4 = __attribute__((ext_vector_type(4))) float;

// bf16 helpers (self-contained, RNE)
static __device__ __forceinline__ unsigned short f2bf(float f) {
  unsigned u = __float_as_uint(f);
  unsigned r = (u + 0x7fff + ((u >> 16) & 1)) >> 16;
  return (unsigned short)r;
}
static __device__ __forceinline__ float bflo(unsigned w) {
  return __uint_as_float(w << 16);
}
static __device__ __forceinline__ float bfhi(unsigned w) {
  return __uint_as_float(w & 0xffff0000u);
}
static __device__ __forceinline__ unsigned pk2(float a, float b) {
  return (unsigned)f2bf(a) | ((unsigned)f2bf(b) << 16);
}

// ======================= scan machinery (chunk=1024, 4/thread) =====================

__global__ void k_scan_chunk(const int* __restrict__ cnt, int* __restrict__ rp,
                             int* __restrict__ bsum, int m) {
  __shared__ int s[256];
  int b = blockIdx.x, t = threadIdx.x;
  int base = b * 1024 + t * 4;
  int v[4];
  int sum = 0;
#pragma unroll
  for (int k = 0; k < 4; ++k) {
    int i = base + k;
    v[k] = (i < m) ? cnt[i] : 0;
    sum += v[k];
  }
  s[t] = sum;
  __syncthreads();
  int mine = sum;
  for (int off = 1; off < 256; off <<= 1) {
    int y = (t >= off) ? s[t - off] : 0;
    __syncthreads();
    s[t] += y;
    __syncthreads();
  }
  int run = s[t] - mine;
  if (t == 255) bsum[b] = s[255];
#pragma unroll
  for (int k = 0; k < 4; ++k) {
    int i = base + k;
    if (i <= m) rp[i] = run;
    run += v[k];
  }
}

// ======================= CSR build: two-phase partition, LDS atomics only ===========
// pcount also zeroes the h1b/h2b guard rows (block 0). Guard rows FULLY zeroed.

__launch_bounds__(256)
__global__ void k_pcount(const int* __restrict__ dst, int* __restrict__ C, int e,
                         int NB, int chunk, unsigned* __restrict__ h1b,
                         unsigned* __restrict__ h2b, int n) {
  __shared__ int h[MAXNB];
  int blk = blockIdx.x, t = threadIdx.x;
  if (blk == 0) {
    if (t < 32) h1b[(size_t)n * 32 + t] = 0u;
    else if (t < 48) h2b[(size_t)n * 16 + (t - 32)] = 0u;
  }
  for (int i = t; i < NB; i += 256) h[i] = 0;
  __syncthreads();
  int beg = blk * chunk;
  int stop = min(e, beg + chunk);
  for (int j = beg + t; j < stop; j += 256) atomicAdd(&h[dst[j] >> 7], 1);
  __syncthreads();
  for (int i = t; i < NB; i += 256) C[i * G1 + blk] = h[i];
}

// partition self-scans bsum in LDS (k_scan_bsum dispatch eliminated)
__launch_bounds__(256)
__global__ void k_partition(const int* __restrict__ src, const int* __restrict__ dst,
                            const int* __restrict__ Cs, const int* __restrict__ bsum,
                            int* __restrict__ bpack, int e, int NB, int chunk,
                            int NC) {
  __shared__ int cur[MAXNB];
  __shared__ int sb[1024];
  __shared__ int ss[256];
  int blk = blockIdx.x, t = threadIdx.x;
  // self-scan bsum[0..NC) -> exclusive prefix in sb
  {
    int b4 = t * 4;
    int v4[4];
    int sum = 0;
#pragma unroll
    for (int k = 0; k < 4; ++k) {
      int i = b4 + k;
      v4[k] = (i < NC) ? bsum[i] : 0;
      sum += v4[k];
    }
    ss[t] = sum;
    __syncthreads();
    int mine = sum;
    for (int off = 1; off < 256; off <<= 1) {
      int y = (t >= off) ? ss[t - off] : 0;
      __syncthreads();
      ss[t] += y;
      __syncthreads();
    }
    int run = ss[t] - mine;
#pragma unroll
    for (int k = 0; k < 4; ++k) {
      int i = b4 + k;
      if (i < 1024) sb[i] = run;
      run += v4[k];
    }
    __syncthreads();
  }
  for (int i = t; i < NB; i += 256) {
    int f = i * G1 + blk;
    cur[i] = Cs[f] + sb[f >> 10];
  }
  __syncthreads();
  int beg = blk * chunk;
  int stop = min(e, beg + chunk);
  for (int j = beg + t; j < stop; j += 256) {
    int d = dst[j];
    int b = d >> 7;
    int pos = atomicAdd(&cur[b], 1);
    bpack[pos] = (src[j] << 7) | (d & 127);
  }
}

// single-pass: bucket edges cached in LDS (fallback to two-pass if oversized)
// self-scans bsum in LDS as well.
__launch_bounds__(256)
__global__ void k_bucket_csr(const int* __restrict__ bpack, const int* __restrict__ Cs,
                             const int* __restrict__ bsum, int* __restrict__ rp,
                             float* __restrict__ dinv, int* __restrict__ csr_src,
                             int n, int e, int NB, int NC) {
  __shared__ int cl[128];
  __shared__ int cur[128];
  __shared__ int buf[BCAP];
  __shared__ int sb[1024];
  __shared__ int ss[256];
  int blk = blockIdx.x, t = threadIdx.x;
  // self-scan bsum
  {
    int b4 = t * 4;
    int v4[4];
    int sum = 0;
#pragma unroll
    for (int k = 0; k < 4; ++k) {
      int i = b4 + k;
      v4[k] = (i < NC) ? bsum[i] : 0;
      sum += v4[k];
    }
    ss[t] = sum;
    __syncthreads();
    int mine = sum;
    for (int off = 1; off < 256; off <<= 1) {
      int y = (t >= off) ? ss[t - off] : 0;
      __syncthreads();
      ss[t] += y;
      __syncthreads();
    }
    int run = ss[t] - mine;
#pragma unroll
    for (int k = 0; k < 4; ++k) {
      int i = b4 + k;
      if (i < 1024) sb[i] = run;
      run += v4[k];
    }
  }
  int fb = blk * G1;
  int base, end;
  if (t < 128) cl[t] = 0;
  __syncthreads();
  base = Cs[fb] + sb[fb >> 10];
  if (blk == NB - 1) {
    end = e;
  } else {
    int fe = (blk + 1) * G1;
    end = Cs[fe] + sb[fe >> 10];
  }
  int cnt = end - base;
  if (cnt <= BCAP) {
    for (int j = base + t; j < end; j += 256) {
      int p = bpack[j];
      buf[j - base] = p;
      atomicAdd(&cl[p & 127], 1);
    }
  } else {
    for (int j = base + t; j < end; j += 256) atomicAdd(&cl[bpack[j] & 127], 1);
  }
  __syncthreads();
  int own = (t < 128) ? cl[t] : 0;
  for (int off = 1; off < 128; off <<= 1) {
    int y = (t >= off && t < 128) ? cl[t - off] : 0;
    __syncthreads();
    if (t < 128) cl[t] += y;
    __syncthreads();
  }
  if (t < 128) {
    int excl = cl[t] - own;
    int v = (blk << 7) + t;
    if (v < n) {
      rp[v] = base + excl;
      dinv[v] = rsqrtf((float)own + 1.0f);
    }
    cur[t] = base + excl;
  }
  __syncthreads();
  if (cnt <= BCAP) {
    for (int j = t; j < cnt; j += 256) {
      int p = buf[j];
      int pos = atomicAdd(&cur[p & 127], 1);
      csr_src[pos] = p >> 7;
    }
  } else {
    for (int j = base + t; j < end; j += 256) {
      int p = bpack[j];
      int pos = atomicAdd(&cur[p & 127], 1);
      csr_src[pos] = p >> 7;
    }
  }
  if (blk == 0 && t == 0) rp[n] = e;
}

// ======================= GEMM1 (MFMA): h1b[n][64](bf16) = dinv[r]*(x @ W1^T) ======

__launch_bounds__(256)
__global__ void k_gemm1(const float* __restrict__ x, const float* __restrict__ W1,
                        const float* __restrict__ dinv, unsigned short* __restrict__ h1b,
                        int n) {
  __shared__ uint4 sXb[64 * 16];                       // 16 KB
  __shared__ uint4 sWb[64 * 16];                       // 16 KB
  __shared__ __align__(16) unsigned short sOut[64 * 64];  // 8 KB
  int t = threadIdx.x;
  const float4* x4 = (const float4*)x;
  const float4* W14 = (const float4*)W1;
  int rbase = blockIdx.x * 64;
#pragma unroll
  for (int p = 0; p < 4; ++p) {
    int q = t + 256 * p;
    int r = q >> 4, s = q & 15;
    int gr = rbase + r;
    float4 v0 = make_float4(0.f, 0.f, 0.f, 0.f), v1 = v0;
    if (gr < n) {
      v0 = x4[(size_t)gr * 32 + s * 2];
      v1 = x4[(size_t)gr * 32 + s * 2 + 1];
    }
    uint4 pk;
    pk.x = pk2(v0.x, v0.y);
    pk.y = pk2(v0.z, v0.w);
    pk.z = pk2(v1.x, v1.y);
    pk.w = pk2(v1.z, v1.w);
    sXb[r * 16 + (s ^ (r & 15))] = pk;
  }
#pragma unroll
  for (int p = 0; p < 4; ++p) {
    int q = t + 256 * p;
    int c = q >> 4, s = q & 15;
    float4 v0 = W14[c * 32 + s * 2];
    float4 v1 = W14[c * 32 + s * 2 + 1];
    uint4 pk;
    pk.x = pk2(v0.x, v0.y);
    pk.y = pk2(v0.z, v0.w);
    pk.z = pk2(v1.x, v1.y);
    pk.w = pk2(v1.z, v1.w);
    sWb[c * 16 + (s ^ (c & 15))] = pk;
  }
  __syncthreads();
  int lane = t & 63;
  int w = t >> 6;
  int l16 = lane & 15, quad = lane >> 4;
  int arow = w * 16 + l16;
  f32x4 acc0 = {0.f, 0.f, 0.f, 0.f};
  f32x4 acc1 = {0.f, 0.f, 0.f, 0.f};
  f32x4 acc2 = {0.f, 0.f, 0.f, 0.f};
  f32x4 acc3 = {0.f, 0.f, 0.f, 0.f};
#pragma unroll
  for (int kc = 0; kc < 4; ++kc) {
    int slot = kc * 4 + quad;
    uint4 ua = sXb[arow * 16 + (slot ^ (arow & 15))];
    bf16x8 a = *(bf16x8*)&ua;
    uint4 ub0 = sWb[(0 + l16) * 16 + (slot ^ l16)];
    uint4 ub1 = sWb[(16 + l16) * 16 + (slot ^ l16)];
    uint4 ub2 = sWb[(32 + l16) * 16 + (slot ^ l16)];
    uint4 ub3 = sWb[(48 + l16) * 16 + (slot ^ l16)];
    acc0 = __builtin_amdgcn_mfma_f32_16x16x32_bf16(a, *(bf16x8*)&ub0, acc0, 0, 0, 0);
    acc1 = __builtin_amdgcn_mfma_f32_16x16x32_bf16(a, *(bf16x8*)&ub1, acc1, 0, 0, 0);
    acc2 = __builtin_amdgcn_mfma_f32_16x16x32_bf16(a, *(bf16x8*)&ub2, acc2, 0, 0, 0);
    acc3 = __builtin_amdgcn_mfma_f32_16x16x32_bf16(a, *(bf16x8*)&ub3, acc3, 0, 0, 0);
  }
  float dvr[4];
#pragma unroll
  for (int r = 0; r < 4; ++r) {
    int grow = rbase + w * 16 + quad * 4 + r;
    dvr[r] = (grow < n) ? dinv[grow] : 0.f;
  }
#pragma unroll
  for (int r = 0; r < 4; ++r) {
    int rl = w * 16 + quad * 4 + r;
    sOut[rl * 64 + 0 + l16] = f2bf(acc0[r] * dvr[r]);
    sOut[rl * 64 + 16 + l16] = f2bf(acc1[r] * dvr[r]);
    sOut[rl * 64 + 32 + l16] = f2bf(acc2[r] * dvr[r]);
    sOut[rl * 64 + 48 + l16] = f2bf(acc3[r] * dvr[r]);
  }
  __syncthreads();
#pragma unroll
  for (int p = 0; p < 2; ++p) {
    int q = t + 256 * p;
    int r = q >> 3, s = q & 7;
    int gr = rbase + r;
    if (gr < n)
      *(uint4*)&h1b[(size_t)gr * 64 + s * 8] = *(uint4*)&sOut[r * 64 + s * 8];
  }
}

// ===== fused agg1+gemm2: gather h1b -> relu(+b1) -> MFMA @ W2^T -> h2b ===========
// (structure lifted from the correctness-verified mega P6 phase)

__launch_bounds__(256)
__global__ void k_fused(const unsigned* __restrict__ h1p, const float* __restrict__ b1,
                        const float* __restrict__ W2, const float* __restrict__ dinv,
                        const int* __restrict__ rp, const int* __restrict__ csr_src,
                        unsigned short* __restrict__ h2b, int n) {
  __shared__ uint4 sXb2[64 * 8];                        // 8 KB: 64 rows x 64 bf16
  __shared__ uint4 sWb2[32 * 8];                        // 4 KB
  __shared__ __align__(16) unsigned short sOut2[64 * 32];  // 4 KB
  int t = threadIdx.x;
  int rbase = blockIdx.x * 64;
  const uint2* h1q = (const uint2*)h1p;
  const float4* W24 = (const float4*)W2;
  const float4* b14 = (const float4*)b1;
  // stage W2
  {
    int c = t >> 3, s2 = t & 7;
    float4 v0 = W24[c * 16 + s2 * 2];
    float4 v1 = W24[c * 16 + s2 * 2 + 1];
    uint4 pk;
    pk.x = pk2(v0.x, v0.y);
    pk.y = pk2(v0.z, v0.w);
    pk.z = pk2(v1.x, v1.y);
    pk.w = pk2(v1.z, v1.w);
    sWb2[c * 8 + (s2 ^ (c & 7))] = pk;
  }
  int f4 = t & 15;
  int rloc = t >> 4;
#pragma unroll
  for (int sub = 0; sub < 4; ++sub) {
    int r = sub * 16 + rloc;
    int v = rbase + r;
    float r0 = 0.f, r1 = 0.f, r2 = 0.f, r3 = 0.f;
    if (v < n) {
      int beg = rp[v], end = rp[v + 1];
      uint2 w0 = h1q[(size_t)v * 16 + f4];  // self (pre-scaled by dinv[v])
      float acc[4][4];
#pragma unroll
      for (int k = 0; k < 4; ++k)
#pragma unroll
        for (int c = 0; c < 4; ++c) acc[k][c] = 0.f;
      acc[0][0] = bflo(w0.x);
      acc[0][1] = bfhi(w0.x);
      acc[0][2] = bflo(w0.y);
      acc[0][3] = bfhi(w0.y);
      for (int j = beg; j < end; j += 4) {
        int s[4];
#pragma unroll
        for (int k = 0; k < 4; ++k) s[k] = csr_src[j + k];
#pragma unroll
        for (int k = 1; k < 4; ++k) s[k] = (j + k < end) ? s[k] : n;
        uint2 g[4];
#pragma unroll
        for (int k = 0; k < 4; ++k) g[k] = h1q[(size_t)s[k] * 16 + f4];
#pragma unroll
        for (int k = 0; k < 4; ++k) {
          acc[k][0] += bflo(g[k].x);
          acc[k][1] += bfhi(g[k].x);
          acc[k][2] += bflo(g[k].y);
          acc[k][3] += bfhi(g[k].y);
        }
      }
      float s0 = (acc[0][0] + acc[1][0]) + (acc[2][0] + acc[3][0]);
      float s1 = (acc[0][1] + acc[1][1]) + (acc[2][1] + acc[3][1]);
      float s2 = (acc[0][2] + acc[1][2]) + (acc[2][2] + acc[3][2]);
      float s3 = (acc[0][3] + acc[1][3]) + (acc[2][3] + acc[3][3]);
      float dv = dinv[v];
      float4 bb = b14[f4];
      r0 = fmaxf(fmaf(dv, s0, bb.x), 0.f);
      r1 = fmaxf(fmaf(dv, s1, bb.y), 0.f);
      r2 = fmaxf(fmaf(dv, s2, bb.z), 0.f);
      r3 = fmaxf(fmaf(dv, s3, bb.w), 0.f);
    }
    unsigned u0 = pk2(r0, r1), u1 = pk2(r2, r3);
    unsigned* xb = (unsigned*)sXb2;
    int slot = (f4 >> 1) ^ (r & 7);
    xb[(r * 8 + slot) * 4 + (f4 & 1) * 2 + 0] = u0;
    xb[(r * 8 + slot) * 4 + (f4 & 1) * 2 + 1] = u1;
  }
  __syncthreads();
  int lane = t & 63;
  int w = t >> 6;
  int l16 = lane & 15, quad = lane >> 4;
  int arow = w * 16 + l16;
  f32x4 acc0 = {0.f, 0.f, 0.f, 0.f};
  f32x4 acc1 = {0.f, 0.f, 0.f, 0.f};
#pragma unroll
  for (int kc = 0; kc < 2; ++kc) {
    int slot = kc * 4 + quad;
    uint4 ua = sXb2[arow * 8 + (slot ^ (arow & 7))];
    bf16x8 a = *(bf16x8*)&ua;
    uint4 ub0 = sWb2[l16 * 8 + (slot ^ (l16 & 7))];
    uint4 ub1 = sWb2[(16 + l16) * 8 + (slot ^ (l16 & 7))];
    acc0 = __builtin_amdgcn_mfma_f32_16x16x32_bf16(a, *(bf16x8*)&ub0, acc0, 0, 0, 0);
    acc1 = __builtin_amdgcn_mfma_f32_16x16x32_bf16(a, *(bf16x8*)&ub1, acc1, 0, 0, 0);
  }
  float dvr[4];
#pragma unroll
  for (int r = 0; r < 4; ++r) {
    int grow = rbase + w * 16 + quad * 4 + r;
    dvr[r] = (grow < n) ? dinv[grow] : 0.f;
  }
#pragma unroll
  for (int r = 0; r < 4; ++r) {
    int rl = w * 16 + quad * 4 + r;
    sOut2[rl * 32 + l16] = f2bf(acc0[r] * dvr[r]);
    sOut2[rl * 32 + 16 + l16] = f2bf(acc1[r] * dvr[r]);
  }
  __syncthreads();
  {
    int r = t >> 2, s2 = t & 3;
    int gr = rbase + r;
    if (gr < n)
      *(uint4*)&h2b[(size_t)gr * 32 + s2 * 8] = *(uint4*)&sOut2[r * 32 + s2 * 8];
  }
}

// ======== agg2: bf16 gather, 8 lanes/node x uint2 (4 feats), unroll 8, fused out ====

__launch_bounds__(256)
__global__ void k_agg2(const unsigned* __restrict__ h2p, const float* __restrict__ dinv,
                       const int* __restrict__ rp, const int* __restrict__ csr_src,
                       const float* __restrict__ b2, float* __restrict__ out, int n) {
  int gid = blockIdx.x * 256 + threadIdx.x;
  int v = gid >> 3, f4 = gid & 7;  // uint2 index within row (4 feats)
  if (v >= n) return;
  const uint2* h2q = (const uint2*)h2p;
  int beg = rp[v], end = rp[v + 1];
  uint2 w0 = h2q[(size_t)v * 8 + f4];  // self
  float acc[8][4];
#pragma unroll
  for (int k = 0; k < 8; ++k)
#pragma unroll
    for (int c = 0; c < 4; ++c) acc[k][c] = 0.f;
  acc[0][0] = bflo(w0.x);
  acc[0][1] = bfhi(w0.x);
  acc[0][2] = bflo(w0.y);
  acc[0][3] = bfhi(w0.y);
  for (int j = beg; j < end; j += 8) {
    int s[8];
#pragma unroll
    for (int k = 0; k < 8; ++k) s[k] = csr_src[j + k];
#pragma unroll
    for (int k = 1; k < 8; ++k) s[k] = (j + k < end) ? s[k] : n;
    uint2 g[8];
#pragma unroll
    for (int k = 0; k < 8; ++k) g[k] = h2q[(size_t)s[k] * 8 + f4];
#pragma unroll
    for (int k = 0; k < 8; ++k) {
      acc[k & 3][0] += bflo(g[k].x);
      acc[k & 3][1] += bfhi(g[k].x);
      acc[k & 3][2] += bflo(g[k].y);
      acc[k & 3][3] += bfhi(g[k].y);
    }
  }
  float s0 = (acc[0][0] + acc[1][0]) + (acc[2][0] + acc[3][0]);
  float s1 = (acc[0][1] + acc[1][1]) + (acc[2][1] + acc[3][1]);
  float s2 = (acc[0][2] + acc[1][2]) + (acc[2][2] + acc[3][2]);
  float s3 = (acc[0][3] + acc[1][3]) + (acc[2][3] + acc[3][3]);
  float dv = dinv[v];
  float4 bv = ((const float4*)b2)[f4];
  float4 o;
  o.x = fmaf(dv, s0, bv.x);
  o.y = fmaf(dv, s1, bv.y);
  o.z = fmaf(dv, s2, bv.z);
  o.w = fmaf(dv, s3, bv.w);
  ((float4*)out)[(size_t)v * 8 + f4] = o;
}

// ======================= launcher =======================

extern "C" void kernel_launch(void* const* d_in, const int* in_sizes, int n_in,
                              void* d_out, int out_size, void* d_ws, size_t ws_size,
                              hipStream_t stream) {
  const float* x = (const float*)d_in[0];
  const int* ei = (const int*)d_in[1];
  const float* W1 = (const float*)d_in[2];
  const float* b1 = (const float*)d_in[3];
  const float* W2 = (const float*)d_in[4];
  const float* b2 = (const float*)d_in[5];
  float* out = (float*)d_out;

  const int n = in_sizes[0] / 128;  // 100000
  const int e = in_sizes[1] / 2;    // 1600000
  const int* src = ei;
  const int* dst = ei + e;

  const int NB = (n + 127) >> 7;          // coarse buckets (782)
  const int m = NB * G1;                  // count-matrix size
  const int chunk = (e + G1 - 1) / G1;    // edges per partition block
  const int NC = (m + 1 + 1023) / 1024;   // scan chunks

  char* base = (char*)d_ws;
  size_t off = 0;
  auto alloc = [&](size_t bytes) {
    char* p = base + off;
    off = (off + bytes + 255) & ~(size_t)255;
    return p;
  };
  int* C = (int*)alloc((size_t)m * 4);
  int* Cs = (int*)alloc((size_t)(m + 1) * 4);
  int* bsum = (int*)alloc(1024 * 4);
  int* bpack = (int*)alloc((size_t)e * 4);
  int* rp = (int*)alloc((size_t)(n + 1) * 4);
  int* csr_src = (int*)alloc((size_t)(e + 8) * 4);  // +8 pad for unrolled reads
  float* dinv = (float*)alloc((size_t)n * 4);
  unsigned short* h1b = (unsigned short*)alloc((size_t)(n + 1) * 64 * 2);  // bf16
  unsigned short* h2b = (unsigned short*)alloc((size_t)(n + 1) * 32 * 2);  // bf16

  // CSR build (no global atomics); scan_bsum folded into partition/bucket
  k_pcount<<<G1, 256, 0, stream>>>(dst, C, e, NB, chunk, (unsigned*)h1b,
                                   (unsigned*)h2b, n);
  k_scan_chunk<<<NC, 256, 0, stream>>>(C, Cs, bsum, m);
  k_partition<<<G1, 256, 0, stream>>>(src, dst, Cs, bsum, bpack, e, NB, chunk, NC);
  k_bucket_csr<<<NB, 256, 0, stream>>>(bpack, Cs, bsum, rp, dinv, csr_src, n, e, NB,
                                       NC);

  // layer 1 dense transform
  k_gemm1<<<(n + 63) / 64, 256, 0, stream>>>(x, W1, dinv, h1b, n);
  // fused: agg1 + relu(+b1) + gemm2 -> h2b
  k_fused<<<(n + 63) / 64, 256, 0, stream>>>((const unsigned*)h1b, b1, W2, dinv, rp,
                                             csr_src, h2b, n);
  // layer 2 aggregate + b2 -> out
  {
    long long total = (long long)n * 8;
    k_agg2<<<(int)((total + 255) / 256), 256, 0, stream>>>((const unsigned*)h2b, dinv,
                                                           rp, csr_src, b2, out, n);
  }
}